// Round 3
// baseline (91.127 us; speedup 1.0000x reference)
//
#include <hip/hip_runtime.h>

// LengthRegulator, fused single kernel.
// B=32, L=1024, D=512, T=max_len=4096.
// out[b,t,:] = x[b, searchsorted(cumsum(dur[b]), t, 'right'), :], zero for t >= total.
//
// 2048 blocks x 256 threads. Block owns 64 consecutive frames of one row b.
// Prologue (redundant per block, cheap): load dur row (int4), shfl-scan to LDS cum,
// binary-search the 64 frame->token indices into LDS. Copy loop then has no
// global-load dependency chain: idx from LDS, x read near-contiguous, out write
// fully contiguous per block (512 KB).

#define B_ 32
#define L_ 1024
#define D_ 512
#define T_ 4096
#define FPB 64              // frames per block

__global__ __launch_bounds__(256) void lr_fused(const float* __restrict__ x,
                                                const int* __restrict__ dur,
                                                float* __restrict__ out) {
    __shared__ int cum[L_];
    __shared__ int wsum[4];
    __shared__ int sidx[FPB];

    const int tid = threadIdx.x;
    const int b = blockIdx.x >> 6;             // 64 blocks per row
    const int f0 = (blockIdx.x & 63) * FPB;

    // ---- per-row inclusive scan of durations (1024 elems, 256 threads x4) ----
    int4 dv = reinterpret_cast<const int4*>(dur + b * L_)[tid];
    int a0 = max(dv.x, 0), a1 = max(dv.y, 0), a2 = max(dv.z, 0), a3 = max(dv.w, 0);
    int tsum = a0 + a1 + a2 + a3;

    int v = tsum;
    const int lane = tid & 63;
    #pragma unroll
    for (int off = 1; off < 64; off <<= 1) {
        int n = __shfl_up(v, off, 64);
        if (lane >= off) v += n;
    }
    const int wv = tid >> 6;
    if (lane == 63) wsum[wv] = v;
    __syncthreads();
    int woff = 0;
    #pragma unroll
    for (int w = 0; w < 3; ++w)
        if (w < wv) woff += wsum[w];
    const int incl = v + woff;                 // inclusive over threads
    const int e = incl - tsum;                 // exclusive base for this thread's 4
    cum[4 * tid + 0] = e + a0;
    cum[4 * tid + 1] = e + a0 + a1;
    cum[4 * tid + 2] = e + a0 + a1 + a2;
    cum[4 * tid + 3] = incl;
    __syncthreads();

    // ---- frame -> token index for this block's 64 frames ----
    const int total = cum[L_ - 1];
    if (tid < FPB) {
        int t = f0 + tid;
        int idx = -1;                          // -1 => zero-pad frame
        if (t < total) {
            idx = 0;                           // branchless searchsorted(cum, t, 'right')
            #pragma unroll
            for (int s = 512; s > 0; s >>= 1)
                if (cum[idx + s - 1] <= t) idx += s;
        }
        sidx[tid] = idx;
    }
    __syncthreads();

    // ---- copy 64 frames x 512 floats (2 frames per iteration) ----
    const float4* xb = reinterpret_cast<const float4*>(x) + (size_t)b * (L_ * D_ / 4);
    float4* o = reinterpret_cast<float4*>(out) + ((size_t)b * T_ + f0) * (D_ / 4);
    const int slot = tid & 127;                // float4 slot within frame
    const int fhalf = tid >> 7;                // 0 or 1

    #pragma unroll 4
    for (int it = 0; it < 32; ++it) {
        const int fl = it * 2 + fhalf;         // local frame 0..63
        const int id = sidx[fl];
        float4 val = make_float4(0.f, 0.f, 0.f, 0.f);
        if (id >= 0) val = xb[id * 128 + slot];
        o[(size_t)fl * 128 + slot] = val;
    }
}

extern "C" void kernel_launch(void* const* d_in, const int* in_sizes, int n_in,
                              void* d_out, int out_size, void* d_ws, size_t ws_size,
                              hipStream_t stream) {
    const float* x = (const float*)d_in[0];
    const int* dur = (const int*)d_in[1];
    // d_in[2] is max_len (== 4096), compile-time constant here.
    float* out = (float*)d_out;

    lr_fused<<<B_ * (T_ / FPB), 256, 0, stream>>>(x, dur, out);
}

// Round 4
// 75.234 us; speedup vs baseline: 1.2113x; 1.2113x over previous
//
#include <hip/hip_runtime.h>

// LengthRegulator: B=32, L=1024, D=512, T=max_len=4096
// out[b,t,:] = x[b, idx(b,t), :] where idx = searchsorted(cumsum(dur[b]), t, 'right'),
// zeroed for t >= total duration of row b.
//
// Kernel 1: per-row scan (shfl) + COALESCED idxmap build via LDS binary search.
// Kernel 2: grid-stride gather (proven round-2 structure, unchanged).

#define B_ 32
#define L_ 1024
#define D_ 512
#define T_ 4096

// One block per row, 1024 threads. Scan durations -> cum in LDS, then each
// thread binary-searches 4 frames and stores idxmap coalesced.
__global__ __launch_bounds__(L_) void lr_scan_map(const int* __restrict__ dur,
                                                  int* __restrict__ idxmap) {
    __shared__ int cum[L_];
    __shared__ int wsum[16];             // 16 waves of 64
    const int b = blockIdx.x;
    const int i = threadIdx.x;
    const int lane = i & 63;
    const int wave = i >> 6;

    int d = dur[b * L_ + i];
    if (d < 0) d = 0;

    // Inclusive scan within the 64-lane wave (no barriers).
    int v = d;
    #pragma unroll
    for (int off = 1; off < 64; off <<= 1) {
        int n = __shfl_up(v, off, 64);
        if (lane >= off) v += n;
    }
    if (lane == 63) wsum[wave] = v;
    __syncthreads();

    // Wave 0 scans the 16 per-wave totals.
    if (wave == 0 && lane < 16) {
        int w = wsum[lane];
        #pragma unroll
        for (int off = 1; off < 16; off <<= 1) {
            int n = __shfl_up(w, off, 64);
            if (lane >= off) w += n;
        }
        wsum[lane] = w;                  // inclusive per-wave totals
    }
    __syncthreads();

    const int waveoff = (wave == 0) ? 0 : wsum[wave - 1];
    cum[i] = v + waveoff;
    __syncthreads();

    const int total = cum[L_ - 1];

    // Each thread resolves 4 frames: t = i, i+1024, i+2048, i+3072.
    // Independent binary searches (ILP overlaps the dependent LDS chains);
    // stores are perfectly coalesced across lanes.
    #pragma unroll
    for (int k = 0; k < 4; ++k) {
        const int t = i + k * L_;
        int idx = -1;                    // -1 => zero-pad frame
        if (t < total) {
            idx = 0;                     // searchsorted(cum, t, 'right')
            #pragma unroll
            for (int s = 512; s > 0; s >>= 1)
                if (cum[idx + s - 1] <= t) idx += s;
        }
        idxmap[b * T_ + t] = idx;
    }
}

// Kernel 2: gather, grid-stride over float4 slots (unchanged from round 2).
// 2048 blocks x 256 threads; iteration `it` sweeps exactly row b=it, so x
// reads stay L2/L3-resident and stores are one contiguous 8 MB sweep per it.
__global__ __launch_bounds__(256) void lr_gather(const float* __restrict__ x,
                                                 const int* __restrict__ idxmap,
                                                 float* __restrict__ out) {
    const int total4 = B_ * T_ * (D_ / 4);     // 16,777,216 float4 slots
    const int stride = gridDim.x * 256;
    float4* o = reinterpret_cast<float4*>(out);

    for (int g = blockIdx.x * 256 + threadIdx.x; g < total4; g += stride) {
        const int bt = g >> 7;                 // D_/4 = 128 slots per frame
        const int slot = g & 127;
        const int b = bt >> 12;                // T_ = 4096
        const int id = idxmap[bt];
        float4 v = make_float4(0.f, 0.f, 0.f, 0.f);
        if (id >= 0) {
            v = reinterpret_cast<const float4*>(
                    x + ((size_t)((b << 10) + id)) * D_)[slot];
        }
        o[g] = v;
    }
}

extern "C" void kernel_launch(void* const* d_in, const int* in_sizes, int n_in,
                              void* d_out, int out_size, void* d_ws, size_t ws_size,
                              hipStream_t stream) {
    const float* x = (const float*)d_in[0];
    const int* dur = (const int*)d_in[1];
    // d_in[2] is max_len (== 4096), compile-time constant here.
    float* out = (float*)d_out;
    int* idxmap = (int*)d_ws;                  // B_*T_ ints = 512 KiB scratch

    lr_scan_map<<<B_, L_, 0, stream>>>(dur, idxmap);
    lr_gather<<<2048, 256, 0, stream>>>(x, idxmap, out);
}

// Round 6
// 73.729 us; speedup vs baseline: 1.2360x; 1.0204x over previous
//
#include <hip/hip_runtime.h>

// LengthRegulator: B=32, L=1024, D=512, T=max_len=4096
// out[b,t,:] = x[b, idx(b,t), :] where idx = searchsorted(cumsum(dur[b]), t, 'right'),
// zeroed for t >= total duration of row b.
//
// Kernel 1: per-row scan (shfl) + coalesced idxmap build via LDS binary search.
// Kernel 2: gather. Fixed (t,slot) per thread, walks b=0..31; all 32 idx
//           preloaded (independent), copy loop unrolled x8 for MLP; NT stores.

#define B_ 32
#define L_ 1024
#define D_ 512
#define T_ 4096
#define GRID_ 2048

typedef float fx4 __attribute__((ext_vector_type(4)));   // native vec for NT store

// One block per row, 1024 threads. Scan durations -> cum in LDS, then each
// thread binary-searches 4 frames and stores idxmap coalesced.
__global__ __launch_bounds__(L_) void lr_scan_map(const int* __restrict__ dur,
                                                  int* __restrict__ idxmap) {
    __shared__ int cum[L_];
    __shared__ int wsum[16];             // 16 waves of 64
    const int b = blockIdx.x;
    const int i = threadIdx.x;
    const int lane = i & 63;
    const int wave = i >> 6;

    int d = dur[b * L_ + i];
    if (d < 0) d = 0;

    // Inclusive scan within the 64-lane wave (no barriers).
    int v = d;
    #pragma unroll
    for (int off = 1; off < 64; off <<= 1) {
        int n = __shfl_up(v, off, 64);
        if (lane >= off) v += n;
    }
    if (lane == 63) wsum[wave] = v;
    __syncthreads();

    // Wave 0 scans the 16 per-wave totals.
    if (wave == 0 && lane < 16) {
        int w = wsum[lane];
        #pragma unroll
        for (int off = 1; off < 16; off <<= 1) {
            int n = __shfl_up(w, off, 64);
            if (lane >= off) w += n;
        }
        wsum[lane] = w;                  // inclusive per-wave totals
    }
    __syncthreads();

    const int waveoff = (wave == 0) ? 0 : wsum[wave - 1];
    cum[i] = v + waveoff;
    __syncthreads();

    const int total = cum[L_ - 1];

    // Each thread resolves 4 frames; coalesced stores.
    #pragma unroll
    for (int k = 0; k < 4; ++k) {
        const int t = i + k * L_;
        int idx = -1;                    // -1 => zero-pad frame
        if (t < total) {
            idx = 0;                     // searchsorted(cum, t, 'right')
            #pragma unroll
            for (int s = 512; s > 0; s >>= 1)
                if (cum[idx + s - 1] <= t) idx += s;
        }
        idxmap[b * T_ + t] = idx;
    }
}

// Kernel 2: 2048 blocks x 256 threads. Thread owns (t, slot) and iterates all
// 32 rows b. idx loads are all independent (preloaded); x loads unrolled x8.
__global__ __launch_bounds__(256) void lr_gather(const float* __restrict__ x,
                                                 const int* __restrict__ idxmap,
                                                 float* __restrict__ out) {
    const int g = blockIdx.x * 256 + threadIdx.x;   // [0, 524288)
    const int t = g >> 7;                           // frame within row
    const int slot = g & 127;                       // float4 slot within frame
    const fx4* x4 = reinterpret_cast<const fx4*>(x);
    fx4* o = reinterpret_cast<fx4*>(out);

    int idx[B_];
    #pragma unroll
    for (int b = 0; b < B_; ++b)
        idx[b] = idxmap[b * T_ + t];                // independent, L2-hot

    #pragma unroll 8
    for (int b = 0; b < B_; ++b) {
        fx4 v = {0.f, 0.f, 0.f, 0.f};
        const int id = idx[b];
        if (id >= 0)
            v = x4[((size_t)((b << 10) + id)) * 128 + slot];
        __builtin_nontemporal_store(v, &o[(size_t)(b * T_ + t) * 128 + slot]);
    }
}

extern "C" void kernel_launch(void* const* d_in, const int* in_sizes, int n_in,
                              void* d_out, int out_size, void* d_ws, size_t ws_size,
                              hipStream_t stream) {
    const float* x = (const float*)d_in[0];
    const int* dur = (const int*)d_in[1];
    // d_in[2] is max_len (== 4096), compile-time constant here.
    float* out = (float*)d_out;
    int* idxmap = (int*)d_ws;                       // B_*T_ ints = 512 KiB scratch

    lr_scan_map<<<B_, L_, 0, stream>>>(dur, idxmap);
    lr_gather<<<GRID_, 256, 0, stream>>>(x, idxmap, out);
}

// Round 8
// 70.890 us; speedup vs baseline: 1.2855x; 1.0400x over previous
//
#include <hip/hip_runtime.h>

// LengthRegulator: B=32, L=1024, D=512, T=max_len=4096
// out[b,t,:] = x[b, searchsorted(cumsum(dur[b]), t, 'right'), :], zero for t >= total.
//
// SCATTER formulation: each token's 512-float vector is read ONCE (sequential)
// and written to its contiguous output frame range [cum[k-1], min(cum[k],T)).
// Kernel 1: per-row shfl scan -> cum (32x1024 ints in d_ws).
// Kernel 2: 4096 scatter blocks (8 tokens each) + 512 zero-fill blocks.
//           All control values are block-uniform (no lane divergence).

#define B_ 32
#define L_ 1024
#define D_ 512
#define T_ 4096
#define TPC 8                 // tokens per scatter block
#define NCHUNK (L_ / TPC)     // 128 scatter blocks per row
#define NZ 16                 // zero-fill blocks per row (256 frames each)

typedef float fx4 __attribute__((ext_vector_type(4)));

// Kernel 1: per-row inclusive scan of durations -> cum. 32 blocks x 256 thr.
__global__ __launch_bounds__(256) void lr_scan(const int* __restrict__ dur,
                                               int* __restrict__ cumg) {
    __shared__ int wsum[4];
    const int b = blockIdx.x;
    const int tid = threadIdx.x;

    int4 dv = reinterpret_cast<const int4*>(dur + b * L_)[tid];
    const int a0 = max(dv.x, 0), a1 = max(dv.y, 0);
    const int a2 = max(dv.z, 0), a3 = max(dv.w, 0);
    const int tsum = a0 + a1 + a2 + a3;

    int v = tsum;
    const int lane = tid & 63;
    #pragma unroll
    for (int off = 1; off < 64; off <<= 1) {
        int n = __shfl_up(v, off, 64);
        if (lane >= off) v += n;
    }
    const int wv = tid >> 6;
    if (lane == 63) wsum[wv] = v;
    __syncthreads();
    int woff = 0;
    #pragma unroll
    for (int w = 0; w < 3; ++w)
        if (w < wv) woff += wsum[w];
    const int incl = v + woff;
    const int e = incl - tsum;

    int4 cv;
    cv.x = e + a0; cv.y = e + a0 + a1; cv.z = e + a0 + a1 + a2; cv.w = incl;
    reinterpret_cast<int4*>(cumg + b * L_)[tid] = cv;
}

// Kernel 2: scatter + zero-fill. 4608 blocks x 256 threads.
__global__ __launch_bounds__(256) void lr_scatter(const float* __restrict__ x,
                                                  const int* __restrict__ cumg,
                                                  float* __restrict__ out) {
    const int tid = threadIdx.x;
    const int slot = tid & 127;          // float4 slot within frame
    const int fhalf = tid >> 7;          // 0 or 1: frame parity
    fx4* o = reinterpret_cast<fx4*>(out);

    if (blockIdx.x < B_ * NCHUNK) {
        // ---- scatter: tokens [k0, k0+8) of row b ----
        const int b = blockIdx.x >> 7;   // / NCHUNK
        const int c = blockIdx.x & (NCHUNK - 1);
        const int k0 = c * TPC;

        __shared__ int S[TPC + 1];       // S[j] = frames before token k0+j
        if (tid <= TPC) {
            const int q = k0 + tid - 1;
            S[tid] = (q < 0) ? 0 : cumg[b * L_ + q];
        }
        __syncthreads();

        const fx4* xb = reinterpret_cast<const fx4*>(x) + (size_t)b * (L_ * D_ / 4);

        #pragma unroll
        for (int j = 0; j < TPC; ++j) {
            int lo = S[j], hi = S[j + 1];
            if (lo >= T_) break;         // cum monotone: later tokens also out
            if (hi > T_) hi = T_;
            if (lo >= hi) continue;      // zero-duration token
            const fx4 v = xb[(k0 + j) * 128 + slot];   // sequential, read once
            for (int f = lo + fhalf; f < hi; f += 2)
                __builtin_nontemporal_store(v, &o[((size_t)(b * T_ + f)) * 128 + slot]);
        }
    } else {
        // ---- zero-fill frames [total_b, T_) ----
        const int z = blockIdx.x - B_ * NCHUNK;
        const int b = z >> 4;
        const int seg = z & (NZ - 1);
        const int total = cumg[b * L_ + L_ - 1];
        int lo = seg * (T_ / NZ);
        const int hi = lo + (T_ / NZ);
        if (lo < total) lo = total;
        const fx4 zv = {0.f, 0.f, 0.f, 0.f};
        for (int f = lo + fhalf; f < hi; f += 2)
            __builtin_nontemporal_store(zv, &o[((size_t)(b * T_ + f)) * 128 + slot]);
    }
}

extern "C" void kernel_launch(void* const* d_in, const int* in_sizes, int n_in,
                              void* d_out, int out_size, void* d_ws, size_t ws_size,
                              hipStream_t stream) {
    const float* x = (const float*)d_in[0];
    const int* dur = (const int*)d_in[1];
    // d_in[2] is max_len (== 4096), compile-time constant here.
    float* out = (float*)d_out;
    int* cumg = (int*)d_ws;              // B_*L_ ints = 128 KiB scratch

    lr_scan<<<B_, 256, 0, stream>>>(dur, cumg);
    lr_scatter<<<B_ * NCHUNK + B_ * NZ, 256, 0, stream>>>(x, cumg, out);
}

// Round 9
// 64.094 us; speedup vs baseline: 1.4218x; 1.1060x over previous
//
#include <hip/hip_runtime.h>

// LengthRegulator: B=32, L=1024, D=512, T=max_len=4096
// out[b,t,:] = x[b, searchsorted(cumsum(dur[b]), t, 'right'), :], zero for t >= total.
//
// Kernel 1: per-row shfl scan + coalesced idxmap build via LDS binary search
//           (proven round-4 code, ~3 us).
// Kernel 2: ONE-ROUND balanced scatter. Exactly 2048 blocks (8/CU, one
//           scheduling round). Block owns 2 chunks x 32 consecutive frames
//           (= 128 KB of writes, identical for every block). Frame->token ids
//           staged in LDS; x re-read only when id changes (wave-uniform
//           dedup -> each token read ~once); NT stores; pad frames (-1)
//           write a zero vector. No separate zero-fill pass, no tail round.

#define B_ 32
#define L_ 1024
#define D_ 512
#define T_ 4096

typedef float fx4 __attribute__((ext_vector_type(4)));

// One block per row, 1024 threads. Scan durations -> cum in LDS, then each
// thread binary-searches 4 frames and stores idxmap coalesced.
__global__ __launch_bounds__(L_) void lr_scan_map(const int* __restrict__ dur,
                                                  int* __restrict__ idxmap) {
    __shared__ int cum[L_];
    __shared__ int wsum[16];             // 16 waves of 64
    const int b = blockIdx.x;
    const int i = threadIdx.x;
    const int lane = i & 63;
    const int wave = i >> 6;

    int d = dur[b * L_ + i];
    if (d < 0) d = 0;

    // Inclusive scan within the 64-lane wave (no barriers).
    int v = d;
    #pragma unroll
    for (int off = 1; off < 64; off <<= 1) {
        int n = __shfl_up(v, off, 64);
        if (lane >= off) v += n;
    }
    if (lane == 63) wsum[wave] = v;
    __syncthreads();

    // Wave 0 scans the 16 per-wave totals.
    if (wave == 0 && lane < 16) {
        int w = wsum[lane];
        #pragma unroll
        for (int off = 1; off < 16; off <<= 1) {
            int n = __shfl_up(w, off, 64);
            if (lane >= off) w += n;
        }
        wsum[lane] = w;                  // inclusive per-wave totals
    }
    __syncthreads();

    const int waveoff = (wave == 0) ? 0 : wsum[wave - 1];
    cum[i] = v + waveoff;
    __syncthreads();

    const int total = cum[L_ - 1];

    // Each thread resolves 4 frames; coalesced stores.
    #pragma unroll
    for (int k = 0; k < 4; ++k) {
        const int t = i + k * L_;
        int idx = -1;                    // -1 => zero-pad frame
        if (t < total) {
            idx = 0;                     // searchsorted(cum, t, 'right')
            #pragma unroll
            for (int s = 512; s > 0; s >>= 1)
                if (cum[idx + s - 1] <= t) idx += s;
        }
        idxmap[b * T_ + t] = idx;
    }
}

// Kernel 2: 2048 blocks x 256 threads, one scheduling round, equal work.
__global__ __launch_bounds__(256) void lr_scatter(const float* __restrict__ x,
                                                  const int* __restrict__ idxmap,
                                                  float* __restrict__ out) {
    __shared__ int ids[64];              // 2 chunks x 32 frame ids
    const int tid = threadIdx.x;
    const int slot = tid & 127;          // float4 slot within frame
    const int fhalf = tid >> 7;          // 0: even frames, 1: odd frames (wave-uniform)

    if (tid < 64) {
        const int chunk = blockIdx.x * 2 + (tid >> 5);
        ids[tid] = idxmap[chunk * 32 + (tid & 31)];   // chunk*32 == b*T_ + f0
    }
    __syncthreads();

    const fx4* x4 = reinterpret_cast<const fx4*>(x);
    fx4* o = reinterpret_cast<fx4*>(out);

    #pragma unroll
    for (int c = 0; c < 2; ++c) {
        const int chunk = blockIdx.x * 2 + c;         // 0..4095
        const int b = chunk >> 7;                     // 128 chunks per row
        const fx4* xb = x4 + (size_t)b * (L_ * D_ / 4);
        fx4* ob = o + (size_t)chunk * 32 * 128;       // 32 frames x 128 slots

        int prev = -2;                                // != any id and != -1
        fx4 v = {0.f, 0.f, 0.f, 0.f};
        #pragma unroll
        for (int i2 = 0; i2 < 16; ++i2) {
            const int fi = 2 * i2 + fhalf;            // frame within chunk
            const int id = ids[c * 32 + fi];          // broadcast from LDS
            if (id != prev) {                         // wave-uniform branch
                if (id >= 0) v = xb[id * 128 + slot]; // token read (deduped)
                else         v = (fx4){0.f, 0.f, 0.f, 0.f};
                prev = id;
            }
            __builtin_nontemporal_store(v, &ob[fi * 128 + slot]);
        }
    }
}

extern "C" void kernel_launch(void* const* d_in, const int* in_sizes, int n_in,
                              void* d_out, int out_size, void* d_ws, size_t ws_size,
                              hipStream_t stream) {
    const float* x = (const float*)d_in[0];
    const int* dur = (const int*)d_in[1];
    // d_in[2] is max_len (== 4096), compile-time constant here.
    float* out = (float*)d_out;
    int* idxmap = (int*)d_ws;            // B_*T_ ints = 512 KiB scratch

    lr_scan_map<<<B_, L_, 0, stream>>>(dur, idxmap);
    lr_scatter<<<2048, 256, 0, stream>>>(x, idxmap, out);
}